// Round 1
// baseline (696.994 us; speedup 1.0000x reference)
//
#include <hip/hip_runtime.h>
#include <math.h>

// GATConv forward, decomposed:
//   k_transpose_w : Wt[k][n] = W[n][k]            (256x256, trivial)
//   k_gemm_el_er  : feat_src = feat @ W.T  (fp32 vector GEMM, VALU-bound)
//                   + fused el/er = sum_d feat_src * attn_{l,r}   [N,H]
//   k_aggregate   : per-dst edge softmax (deg==16) + weighted gather-sum
//
// Layout constants from the reference: N=100000, IN=256, H=4, D=64, E=N*16.
// row_ptr = arange(N+1)*16 -> degree is exactly 16 for every node (kernel
// assumes deg <= 16; guaranteed by setup).

#define HEADS 4
#define KIN 256
#define NOUT 256   // H*D
#define NEG_SLOPE 0.2f

__global__ __launch_bounds__(256) void k_transpose_w(const float* __restrict__ W,
                                                     float* __restrict__ Wt) {
  // W: [NOUT][KIN] row-major; Wt: [KIN][NOUT]
  int n = blockIdx.x;   // 0..255
  int k = threadIdx.x;  // 0..255
  Wt[k * NOUT + n] = W[n * KIN + k];
}

// Wave-per-16-rows fp32 GEMM. Block = 256 threads = 4 waves = 64 rows.
// Lane l holds output columns [4l, 4l+4). Requires n_nodes % 16 == 0 per-wave
// validity (100000 = 16*6250, OK).
__global__ __launch_bounds__(256) void k_gemm_el_er(
    const float* __restrict__ feat, const float* __restrict__ Wt,
    const float* __restrict__ attn_l, const float* __restrict__ attn_r,
    float* __restrict__ feat_src, float* __restrict__ el, float* __restrict__ er,
    int n_nodes) {
  const int lane = threadIdx.x & 63;
  const int wave = threadIdx.x >> 6;
  const int m0 = blockIdx.x * 64 + wave * 16;
  if (m0 >= n_nodes) return;

  const float4* __restrict__ Wt4 = (const float4*)Wt;
  const float* __restrict__ fbase = feat + (size_t)m0 * KIN;

  float4 acc[16];
#pragma unroll
  for (int r = 0; r < 16; ++r) acc[r] = make_float4(0.f, 0.f, 0.f, 0.f);

  for (int k = 0; k < KIN; k += 4) {
    float4 w0 = Wt4[(k + 0) * (NOUT / 4) + lane];
    float4 w1 = Wt4[(k + 1) * (NOUT / 4) + lane];
    float4 w2 = Wt4[(k + 2) * (NOUT / 4) + lane];
    float4 w3 = Wt4[(k + 3) * (NOUT / 4) + lane];
#pragma unroll
    for (int r = 0; r < 16; ++r) {
      float4 f = *(const float4*)(fbase + r * KIN + k);  // wave-uniform addr (broadcast)
      acc[r].x = fmaf(f.x, w0.x, acc[r].x);
      acc[r].y = fmaf(f.x, w0.y, acc[r].y);
      acc[r].z = fmaf(f.x, w0.z, acc[r].z);
      acc[r].w = fmaf(f.x, w0.w, acc[r].w);
      acc[r].x = fmaf(f.y, w1.x, acc[r].x);
      acc[r].y = fmaf(f.y, w1.y, acc[r].y);
      acc[r].z = fmaf(f.y, w1.z, acc[r].z);
      acc[r].w = fmaf(f.y, w1.w, acc[r].w);
      acc[r].x = fmaf(f.z, w2.x, acc[r].x);
      acc[r].y = fmaf(f.z, w2.y, acc[r].y);
      acc[r].z = fmaf(f.z, w2.z, acc[r].z);
      acc[r].w = fmaf(f.z, w2.w, acc[r].w);
      acc[r].x = fmaf(f.w, w3.x, acc[r].x);
      acc[r].y = fmaf(f.w, w3.y, acc[r].y);
      acc[r].z = fmaf(f.w, w3.z, acc[r].z);
      acc[r].w = fmaf(f.w, w3.w, acc[r].w);
    }
  }

  // Epilogue: store feat_src, compute el/er via 16-lane butterfly reduction.
  const float4 al = ((const float4*)attn_l)[lane];
  const float4 ar = ((const float4*)attn_r)[lane];
  float4* __restrict__ fs4 = (float4*)feat_src;
  const int h = lane >> 4;
#pragma unroll
  for (int r = 0; r < 16; ++r) {
    const int m = m0 + r;
    fs4[(size_t)m * (NOUT / 4) + lane] = acc[r];
    float pl = acc[r].x * al.x + acc[r].y * al.y + acc[r].z * al.z + acc[r].w * al.w;
    float pr = acc[r].x * ar.x + acc[r].y * ar.y + acc[r].z * ar.z + acc[r].w * ar.w;
#pragma unroll
    for (int off = 1; off < 16; off <<= 1) {
      pl += __shfl_xor(pl, off, 64);
      pr += __shfl_xor(pr, off, 64);
    }
    if ((lane & 15) == 0) {
      el[m * HEADS + h] = pl;
      er[m * HEADS + h] = pr;
    }
  }
}

// One wave per dst node. Softmax phase: lane = h*16 + j (head h, edge j).
// Accumulate phase: lane = float4 chunk of the 256-float output row
// (head = lane>>4 in both phases, so softmax weights broadcast in-group).
__global__ __launch_bounds__(256) void k_aggregate(
    const int* __restrict__ row_ptr, const int* __restrict__ col_ind,
    const float* __restrict__ el, const float* __restrict__ er,
    const float* __restrict__ feat_src, float* __restrict__ out, int n_nodes) {
  const int gid = blockIdx.x * blockDim.x + threadIdx.x;
  const int node = gid >> 6;
  const int lane = threadIdx.x & 63;
  if (node >= n_nodes) return;

  const int h = lane >> 4;
  const int j = lane & 15;
  const int rs = row_ptr[node];
  const int deg = row_ptr[node + 1] - rs;  // == 16 by construction

  const bool valid = (j < deg);
  const int src = valid ? col_ind[rs + j] : 0;

  float e = valid ? (er[src * HEADS + h] + el[node * HEADS + h]) : -INFINITY;
  e = (e > 0.f) ? e : NEG_SLOPE * e;  // LeakyReLU

  // max over the 16 edges of this head (lanes h*16 .. h*16+15)
  float mx = e;
#pragma unroll
  for (int off = 1; off < 16; off <<= 1) mx = fmaxf(mx, __shfl_xor(mx, off, 64));
  float ex = valid ? __expf(e - mx) : 0.f;
  float s = ex;
#pragma unroll
  for (int off = 1; off < 16; off <<= 1) s += __shfl_xor(s, off, 64);
  const float a = ex / s;  // softmax weight for (edge j, head h); 0 if invalid

  // Weighted gather-sum: lane covers out[node][4*lane .. 4*lane+4)
  const float4* __restrict__ fs4 = (const float4*)feat_src;
  const int hbase = lane & 48;  // head group base lane
  float4 acc = make_float4(0.f, 0.f, 0.f, 0.f);
#pragma unroll
  for (int j2 = 0; j2 < 16; ++j2) {
    const int sj = __shfl(src, j2, 64);          // src id of edge j2
    const float w = __shfl(a, hbase + j2, 64);   // weight for (j2, my head)
    const float4 v = fs4[(size_t)sj * (NOUT / 4) + lane];  // coalesced 1KB row
    acc.x = fmaf(w, v.x, acc.x);
    acc.y = fmaf(w, v.y, acc.y);
    acc.z = fmaf(w, v.z, acc.z);
    acc.w = fmaf(w, v.w, acc.w);
  }
  ((float4*)out)[(size_t)node * (NOUT / 4) + lane] = acc;
}

extern "C" void kernel_launch(void* const* d_in, const int* in_sizes, int n_in,
                              void* d_out, int out_size, void* d_ws, size_t ws_size,
                              hipStream_t stream) {
  const int* row_ptr = (const int*)d_in[0];
  const int* col_ind = (const int*)d_in[1];
  const float* feat = (const float*)d_in[2];
  const float* W = (const float*)d_in[3];
  const float* attn_l = (const float*)d_in[4];
  const float* attn_r = (const float*)d_in[5];
  float* out = (float*)d_out;
  const int n_nodes = in_sizes[0] - 1;

  // Workspace layout (all fp32):
  //   Wt       : 256*256           = 256 KB
  //   feat_src : n_nodes*256       = 102.4 MB
  //   el, er   : n_nodes*4 each    = 1.6 MB each
  char* ws = (char*)d_ws;
  float* Wt = (float*)ws;
  float* feat_src = (float*)(ws + 256 * 1024);
  size_t fs_bytes = (size_t)n_nodes * NOUT * sizeof(float);
  float* el = (float*)(ws + 256 * 1024 + fs_bytes);
  float* er = el + (size_t)n_nodes * HEADS;

  k_transpose_w<<<256, 256, 0, stream>>>(W, Wt);
  k_gemm_el_er<<<(n_nodes + 63) / 64, 256, 0, stream>>>(
      feat, Wt, attn_l, attn_r, feat_src, el, er, n_nodes);
  k_aggregate<<<(n_nodes + 3) / 4, 256, 0, stream>>>(
      row_ptr, col_ind, el, er, feat_src, out, n_nodes);
}

// Round 2
// 360.433 us; speedup vs baseline: 1.9338x; 1.9338x over previous
//
#include <hip/hip_runtime.h>
#include <math.h>

// GATConv forward:
//   k_cast_w    : Wbf[n][k] = bf16(W[n][k])  (W is [HD=256][IN=256]; this IS
//                 B^T layout for feat @ W.T, so no transpose needed)
//   k_gemm_mfma : feat_src(bf16) = feat @ W.T via mfma_f32_16x16x32_bf16,
//                 fp32 accum; fused el/er = <feat_src, attn_{l,r}> per head
//   k_aggregate : per-dst edge softmax (deg==16) + weighted bf16 gather-sum
//
// N=100000, IN=256, H=4, D=64, E=N*16; degree uniformly 16 (row_ptr=arange*16).

#define HEADS 4
#define KIN 256
#define NOUT 256   // H*D
#define NEG_SLOPE 0.2f
#define BK 32      // K-chunk staged per LDS round
#define SA 40      // A LDS row stride (bf16 elems): 80B -> 2-way bank alias (free)
#define SB 40      // B LDS row stride

typedef __attribute__((ext_vector_type(4))) short short4v;
typedef __attribute__((ext_vector_type(8))) short short8v;
typedef __attribute__((ext_vector_type(4))) float floatx4;

static __device__ __forceinline__ unsigned short f2bf(float x) {
  // round-to-nearest-even fp32 -> bf16 (inputs are normal; no NaN handling)
  unsigned u = __float_as_uint(x);
  u += 0x7FFFu + ((u >> 16) & 1u);
  return (unsigned short)(u >> 16);
}
static __device__ __forceinline__ float bf2f(unsigned short b) {
  return __uint_as_float(((unsigned)b) << 16);
}

__global__ __launch_bounds__(256) void k_cast_w(const float* __restrict__ W,
                                                unsigned short* __restrict__ Wbf) {
  const int i = blockIdx.x * 256 + threadIdx.x;  // float4 index, 16384 total
  float4 f = ((const float4*)W)[i];
  ushort4 o;
  o.x = f2bf(f.x); o.y = f2bf(f.y); o.z = f2bf(f.z); o.w = f2bf(f.w);
  ((ushort4*)Wbf)[i] = o;
}

// Block = 256 threads = 4 waves. Block tile: M=64 rows, N=256 (full width).
// Wave w owns cols [64w, 64w+64) == head w exactly. Per wave: 4x4 grid of
// 16x16 MFMA tiles, K in 8 chunks of 32.
__global__ __launch_bounds__(256) void k_gemm_mfma(
    const float* __restrict__ feat, const unsigned short* __restrict__ Wbf,
    const float* __restrict__ attn_l, const float* __restrict__ attn_r,
    unsigned short* __restrict__ fs_bf, float* __restrict__ el,
    float* __restrict__ er, int n_nodes) {
  __shared__ unsigned short Alds[64 * SA];    // 5120 B
  __shared__ unsigned short Blds[256 * SB];   // 20480 B

  const int tid = threadIdx.x;
  const int lane = tid & 63;
  const int w = tid >> 6;      // wave = head = col-group
  const int m0 = blockIdx.x * 64;
  const int q = lane >> 4;     // quad 0..3
  const int l15 = lane & 15;

  floatx4 acc[4][4];
#pragma unroll
  for (int mt = 0; mt < 4; ++mt)
#pragma unroll
    for (int nt = 0; nt < 4; ++nt)
#pragma unroll
      for (int r = 0; r < 4; ++r) acc[mt][nt][r] = 0.0f;

  // staging maps (chunk-invariant)
  const int a_row = tid >> 3;        // 0..31 (two halves)
  const int a_kk = (tid & 7) * 4;    // 0,4,...,28

  for (int kc = 0; kc < 8; ++kc) {
    const int k0 = kc * BK;
    // ---- stage A: 64 rows x 32 k, fp32 -> bf16, coalesced float4 loads
#pragma unroll
    for (int half = 0; half < 2; ++half) {
      const int row = a_row + half * 32;
      int gr = m0 + row;
      if (gr >= n_nodes) gr = n_nodes - 1;  // clamp tail (rows unused below)
      float4 f = *(const float4*)(feat + (size_t)gr * KIN + k0 + a_kk);
      uint2 p;
      p.x = ((unsigned)f2bf(f.y) << 16) | f2bf(f.x);
      p.y = ((unsigned)f2bf(f.w) << 16) | f2bf(f.z);
      *(uint2*)(&Alds[row * SA + a_kk]) = p;
    }
    // ---- stage B: 256 n-rows x 32 k from Wbf[n][k0..k0+32) (L2-hot)
    {
      const uint4* src = (const uint4*)(Wbf + (size_t)tid * KIN + k0);
      uint2* dst = (uint2*)(&Blds[tid * SB]);
#pragma unroll
      for (int i = 0; i < 4; ++i) {
        uint4 v = src[i];
        dst[2 * i + 0] = make_uint2(v.x, v.y);
        dst[2 * i + 1] = make_uint2(v.z, v.w);
      }
    }
    __syncthreads();
    // ---- fragments: A[m=l15][k=q*8+j], B[k=q*8+j][n=l15]  (Blds is [n][k])
    short8v af[4], bfr[4];
#pragma unroll
    for (int mt = 0; mt < 4; ++mt) {
      const unsigned short* p = &Alds[(mt * 16 + l15) * SA + q * 8];
      short4v lo = *(const short4v*)p;
      short4v hi = *(const short4v*)(p + 4);
      af[mt] = __builtin_shufflevector(lo, hi, 0, 1, 2, 3, 4, 5, 6, 7);
    }
#pragma unroll
    for (int nt = 0; nt < 4; ++nt) {
      const unsigned short* p = &Blds[(w * 64 + nt * 16 + l15) * SB + q * 8];
      short4v lo = *(const short4v*)p;
      short4v hi = *(const short4v*)(p + 4);
      bfr[nt] = __builtin_shufflevector(lo, hi, 0, 1, 2, 3, 4, 5, 6, 7);
    }
#pragma unroll
    for (int mt = 0; mt < 4; ++mt)
#pragma unroll
      for (int nt = 0; nt < 4; ++nt)
        acc[mt][nt] = __builtin_amdgcn_mfma_f32_16x16x32_bf16(
            af[mt], bfr[nt], acc[mt][nt], 0, 0, 0);
    __syncthreads();
  }

  // ---- epilogue: C/D layout col = l15, row = q*4 + r (per 16x16 tile).
  // Store feat_src (bf16) + el/er from fp32 accumulators.
  float alv[4], arv[4];
#pragma unroll
  for (int nt = 0; nt < 4; ++nt) {
    alv[nt] = attn_l[w * 64 + nt * 16 + l15];
    arv[nt] = attn_r[w * 64 + nt * 16 + l15];
  }
#pragma unroll
  for (int mt = 0; mt < 4; ++mt) {
#pragma unroll
    for (int r = 0; r < 4; ++r) {
      const int m = m0 + mt * 16 + q * 4 + r;
      const bool mvalid = (m < n_nodes);
      float pl = 0.f, pr = 0.f;
#pragma unroll
      for (int nt = 0; nt < 4; ++nt) {
        const float v = acc[mt][nt][r];
        pl = fmaf(v, alv[nt], pl);
        pr = fmaf(v, arv[nt], pr);
        if (mvalid)
          fs_bf[(size_t)m * NOUT + w * 64 + nt * 16 + l15] = f2bf(v);
      }
      // reduce over the 16 lanes of this quad (same row m)
#pragma unroll
      for (int off = 1; off < 16; off <<= 1) {
        pl += __shfl_xor(pl, off, 64);
        pr += __shfl_xor(pr, off, 64);
      }
      if (l15 == 0 && mvalid) {
        el[m * HEADS + w] = pl;
        er[m * HEADS + w] = pr;
      }
    }
  }
}

// One wave per dst node. Softmax: lane = h*16 + j. Accumulate: lane = ushort4
// chunk of the 256-col row (head = lane>>4 in both phases).
__global__ __launch_bounds__(256) void k_aggregate(
    const int* __restrict__ row_ptr, const int* __restrict__ col_ind,
    const float* __restrict__ el, const float* __restrict__ er,
    const unsigned short* __restrict__ fs_bf, float* __restrict__ out,
    int n_nodes) {
  const int gid = blockIdx.x * blockDim.x + threadIdx.x;
  const int node = gid >> 6;
  const int lane = threadIdx.x & 63;
  if (node >= n_nodes) return;

  const int h = lane >> 4;
  const int j = lane & 15;
  const int rs = row_ptr[node];
  const int deg = row_ptr[node + 1] - rs;  // == 16 by construction

  const bool valid = (j < deg);
  const int src = valid ? col_ind[rs + j] : 0;

  float e = valid ? (er[src * HEADS + h] + el[node * HEADS + h]) : -INFINITY;
  e = (e > 0.f) ? e : NEG_SLOPE * e;  // LeakyReLU

  float mx = e;
#pragma unroll
  for (int off = 1; off < 16; off <<= 1) mx = fmaxf(mx, __shfl_xor(mx, off, 64));
  float ex = valid ? __expf(e - mx) : 0.f;
  float s = ex;
#pragma unroll
  for (int off = 1; off < 16; off <<= 1) s += __shfl_xor(s, off, 64);
  const float a = ex / s;

  const ushort4* __restrict__ fs4 = (const ushort4*)fs_bf;
  const int hbase = lane & 48;
  float4 acc = make_float4(0.f, 0.f, 0.f, 0.f);
#pragma unroll
  for (int j2 = 0; j2 < 16; ++j2) {
    const int sj = __shfl(src, j2, 64);
    const float wgt = __shfl(a, hbase + j2, 64);
    const ushort4 u = fs4[(size_t)sj * (NOUT / 4) + lane];  // 512B/row coalesced
    acc.x = fmaf(wgt, bf2f(u.x), acc.x);
    acc.y = fmaf(wgt, bf2f(u.y), acc.y);
    acc.z = fmaf(wgt, bf2f(u.z), acc.z);
    acc.w = fmaf(wgt, bf2f(u.w), acc.w);
  }
  ((float4*)out)[(size_t)node * (NOUT / 4) + lane] = acc;
}

extern "C" void kernel_launch(void* const* d_in, const int* in_sizes, int n_in,
                              void* d_out, int out_size, void* d_ws, size_t ws_size,
                              hipStream_t stream) {
  const int* row_ptr = (const int*)d_in[0];
  const int* col_ind = (const int*)d_in[1];
  const float* feat = (const float*)d_in[2];
  const float* W = (const float*)d_in[3];
  const float* attn_l = (const float*)d_in[4];
  const float* attn_r = (const float*)d_in[5];
  float* out = (float*)d_out;
  const int n_nodes = in_sizes[0] - 1;

  // Workspace: Wbf (128 KB) | feat_src bf16 (51.2 MB) | el, er (1.6 MB each)
  char* ws = (char*)d_ws;
  unsigned short* Wbf = (unsigned short*)ws;
  unsigned short* fs_bf = (unsigned short*)(ws + 128 * 1024);
  size_t fs_bytes = (size_t)n_nodes * NOUT * sizeof(unsigned short);
  float* el = (float*)(ws + 128 * 1024 + fs_bytes);
  float* er = el + (size_t)n_nodes * HEADS;

  k_cast_w<<<64, 256, 0, stream>>>(W, Wbf);
  k_gemm_mfma<<<(n_nodes + 63) / 64, 256, 0, stream>>>(
      feat, Wbf, attn_l, attn_r, fs_bf, el, er, n_nodes);
  k_aggregate<<<(n_nodes + 3) / 4, 256, 0, stream>>>(
      row_ptr, col_ind, el, er, fs_bf, out, n_nodes);
}